// Round 15
// baseline (455.420 us; speedup 1.0000x reference)
//
#include <hip/hip_runtime.h>
#include <stdint.h>

#define NTOK 65536
#define DIM  768
#define NCB  512
#define NC   510
#define TAU  1.0f

typedef _Float16 f16x8 __attribute__((ext_vector_type(8)));
typedef float f32x4 __attribute__((ext_vector_type(4)));

// ws byte offsets
#define WS_C32   0u          // 512*768*4
#define WS_CHI   1572864u    // 512*768*2   (f16)
#define WS_CNORM 3145728u    // 512*4
#define WS_G     3147776u    // 512*512*4   (G2 = 2*Gram)
#define WS_IDX   4196352u    // 65536*8*4 (fallback path only)
#define WS_PART  6293504u    // 8192*4 chain loss partials
#define WS_PART2 6359040u    // 2048*4 gemm ||x||^2 partials
#define WS_S     8388608u    // Sq f16: 65536*512*2  (score-form)
#define S_BYTES  67108864u

__device__ __forceinline__ void gl_lds16(const void* g, void* l){
  __builtin_amdgcn_global_load_lds(
      (const __attribute__((address_space(1))) unsigned int*)g,
      (__attribute__((address_space(3))) unsigned int*)l,
      16, 0, 0);
}

__global__ void k_prep(const float* __restrict__ cb0, const float* __restrict__ cb1,
                       const float* __restrict__ cb2, const float* __restrict__ cb3,
                       const float* __restrict__ cb4, const float* __restrict__ cb5,
                       const float* __restrict__ cb6, const float* __restrict__ cb7,
                       char* __restrict__ ws){
  const int r = blockIdx.x, t = threadIdx.x;
  const float* srcs[8] = {cb0,cb1,cb2,cb3,cb4,cb5,cb6,cb7};
  const int off[8] = {0,2,6,14,30,62,126,254};
  const int KK[8]  = {2,4,8,16,32,64,128,256};
  const float* src = nullptr;
#pragma unroll
  for (int l=0;l<8;l++)
    if (r >= off[l] && r < off[l]+KK[l]) src = srcs[l] + (size_t)(r - off[l]) * DIM;
  float* C32 = (float*)(ws + WS_C32);
  _Float16* Chi = (_Float16*)(ws + WS_CHI);
  double ss = 0.0;
#pragma unroll
  for (int i=0;i<3;i++){
    const int e = t + i*256;
    const float v = src ? src[e] : 0.f;
    C32[(size_t)r*DIM + e] = v;
    Chi[(size_t)r*DIM + e] = (_Float16)v;
    ss += (double)v * (double)v;
  }
  __shared__ double red[256];
  red[t] = ss; __syncthreads();
  for (int sdown=128; sdown>0; sdown>>=1){
    if (t < sdown) red[t] += red[t+sdown];
    __syncthreads();
  }
  if (t == 0){
    float* cnp = (float*)(ws + WS_CNORM);
    cnp[r] = (r < NC) ? (float)red[0] : 1e30f;
  }
}

// G2 = 2 * C C^T (f64 accum)
__global__ void k_gram(char* __restrict__ ws){
  const int i = blockIdx.x, t = threadIdx.x;
  const float* __restrict__ C32 = (const float*)(ws + WS_C32);
  __shared__ float row[DIM];
  for (int e=t; e<DIM; e+=256) row[e] = C32[(size_t)i*DIM + e];
  __syncthreads();
  float* __restrict__ G = (float*)(ws + WS_G);
  for (int j=t; j<NCB; j+=256){
    const float4* cj = (const float4*)(C32 + (size_t)j*DIM);
    double d = 0.0;
    for (int k=0; k<DIM/4; k++){
      const float4 b = cj[k];
      d += (double)row[4*k]*(double)b.x + (double)row[4*k+1]*(double)b.y
         + (double)row[4*k+2]*(double)b.z + (double)row[4*k+3]*(double)b.w;
    }
    G[(size_t)i*NCB + j] = (float)(2.0*d);
  }
}

// Sq = f16(cn[c] - 2*(x . c) - 768). R12-validated (best gemm measured).
__global__ __launch_bounds__(256, 3) void k_gemm(const float* __restrict__ x,
                                                 const char* __restrict__ ws,
                                                 _Float16* __restrict__ Sq,
                                                 float* __restrict__ part2){
  __shared__ __align__(16) char smem[49152];   // A f32 [128][64] @0, B f16 [128][64] @32768
  const int t = threadIdx.x, lane = t & 63, w = t >> 6;
  const int wm = w >> 1, wn = w & 1;
  const int bid = blockIdx.x;
  const int xcd = bid & 7, jj = bid >> 3;
  const int mt = xcd*64 + (jj >> 2), nt = jj & 3;
  const _Float16* __restrict__ Chi = (const _Float16*)(ws + WS_CHI);
  const float* __restrict__ cn = (const float*)(ws + WS_CNORM);

  f32x4 acc[4][4];
#pragma unroll
  for (int i=0;i<4;i++)
#pragma unroll
    for (int j=0;j<4;j++) acc[i][j] = {0.f,0.f,0.f,0.f};

  float xs = 0.f;

  for (int kt=0; kt<12; kt++){
#pragma unroll
    for (int i8=0;i8<8;i8++){
      const int r0 = w*32 + i8*4;
      const int row = r0 + (lane>>4);
      const int g = lane & 15;
      const int sg = g ^ (((row&7)<<1) | ((row>>3)&1));
      const size_t go = (size_t)(mt*128 + row)*DIM + (size_t)kt*64 + sg*4;
      gl_lds16(x + go, smem + r0*256);
    }
#pragma unroll
    for (int c4=0;c4<4;c4++){
      const int r0 = w*32 + c4*8;
      const int rloc = r0 + (lane>>3);
      const int jsrc = (lane&7) ^ (rloc&7);
      const size_t go = (size_t)(nt*128 + rloc)*DIM + (size_t)kt*64 + jsrc*8;
      gl_lds16(Chi + go, smem + 32768 + r0*128);
    }
    __syncthreads();
    if ((kt & 3) == nt){
#pragma unroll
      for (int g=0; g<8; g++){
        const f32x4 v = *(const f32x4*)(smem + t*128 + g*16);
        xs += v[0]*v[0] + v[1]*v[1] + v[2]*v[2] + v[3]*v[3];
      }
    }
#pragma unroll
    for (int kk=0; kk<2; kk++){
      f16x8 fa[4], fb[4];
#pragma unroll
      for (int mf=0;mf<4;mf++){
        const int m = wm*64 + mf*16 + (lane&15);
        const int maskm = ((m&7)<<1) | ((m>>3)&1);
        const int ch = kk*4 + (lane>>4);
        const int g0 = (2*ch) ^ maskm;
        const f32x4 lo = *(const f32x4*)(smem + m*256 + g0*16);
        const f32x4 hi = *(const f32x4*)(smem + m*256 + (g0^1)*16);
        f16x8 r;
        r[0]=(_Float16)lo[0]; r[1]=(_Float16)lo[1]; r[2]=(_Float16)lo[2]; r[3]=(_Float16)lo[3];
        r[4]=(_Float16)hi[0]; r[5]=(_Float16)hi[1]; r[6]=(_Float16)hi[2]; r[7]=(_Float16)hi[3];
        fa[mf] = r;
      }
#pragma unroll
      for (int nf=0;nf<4;nf++){
        const int c = wn*64 + nf*16 + (lane&15);
        const uint bb = (uint)(32768 + c*128 + ((((kk<<2)+(lane>>4)) ^ (c&7))*16));
        fb[nf] = *(const f16x8*)(smem + bb);
      }
#pragma unroll
      for (int mf=0;mf<4;mf++)
#pragma unroll
        for (int nf=0;nf<4;nf++)
          acc[mf][nf] = __builtin_amdgcn_mfma_f32_16x16x32_f16(fa[mf], fb[nf], acc[mf][nf], 0,0,0);
    }
    __syncthreads();
  }

#pragma unroll
  for (int d=32; d>0; d>>=1) xs += __shfl_down(xs, d);
  if (lane == 0) ((float*)smem)[w] = xs;
  __syncthreads();
  if (t == 0) part2[bid] = ((float*)smem)[0] + ((float*)smem)[1]
                         + ((float*)smem)[2] + ((float*)smem)[3];

#pragma unroll
  for (int mf=0;mf<4;mf++)
#pragma unroll
    for (int nf=0;nf<4;nf++){
      const f32x4 v = acc[mf][nf];
      const int col  = nt*128 + wn*64 + nf*16 + (lane&15);
      const int row0 = mt*128 + wm*64 + mf*16 + ((lane>>4)<<2);
      const float cnc = cn[col];
#pragma unroll
      for (int e=0;e<4;e++)
        Sq[(size_t)(row0+e)*NCB + col] = (_Float16)(cnc - 2.f*v[e] - 768.f);
    }
}

// Band-rescore argmin chain: TWO tokens per wave, statement-interleaved (ILP x2
// to cover the serial reduce/G2-load latency chains). 16 tokens/block (512thr).
template<int FUSED>
__global__ __launch_bounds__(512, 4) void k_chain(const float* __restrict__ x,
                                                  const _Float16* __restrict__ S,
                                                  char* __restrict__ ws,
                                                  float* __restrict__ out,
                                                  float* __restrict__ part){
  const int t = threadIdx.x, lane = t & 63, w = t >> 6;
  const size_t tokA = (size_t)blockIdx.x*16 + w*2;
  const size_t tokB = tokA + 1;
  const float* __restrict__ cn  = (const float*)(ws + WS_CNORM);
  const float* __restrict__ G2  = (const float*)(ws + WS_G);
  const float* __restrict__ C32 = (const float*)(ws + WS_C32);

  float svA[8], s0A[8], svB[8], s0B[8];
  {
    const uint* spA = (const uint*)(S + tokA*NCB);
    const uint* spB = (const uint*)(S + tokB*NCB);
#pragma unroll
    for (int j=0;j<4;j++){
      union { uint u; _Float16 h[2]; } ca, cb;
      ca.u = spA[j*64 + lane];
      cb.u = spB[j*64 + lane];
      svA[2*j]   = (float)ca.h[0]; svA[2*j+1] = (float)ca.h[1];
      svB[2*j]   = (float)cb.h[0]; svB[2*j+1] = (float)cb.h[1];
    }
  }
#pragma unroll
  for (int k=0;k<8;k++){ s0A[k] = svA[k]; s0B[k] = svB[k]; }

  int mcsA[8], mcsB[8];
  float tot = 0.f;

#pragma unroll
  for (int l=0; l<8; ++l){
    const int cs = (2<<l) - 2;
    const int ce = cs + (2<<l);
    float scA[8], scB[8];
    float bvA = 3e38f, bvB = 3e38f;
    int bcA = 511, bcB = 511;
#pragma unroll
    for (int j=0;j<4;j++){
      const int c0 = j*128 + lane*2;
      const bool in0 = (c0   >= cs && c0   < ce);
      const bool in1 = (c0+1 >= cs && c0+1 < ce);
      const float aA = in0 ? svA[2*j] : 3e38f;
      const float aB = in0 ? svB[2*j] : 3e38f;
      const float bA = in1 ? svA[2*j+1] : 3e38f;
      const float bB = in1 ? svB[2*j+1] : 3e38f;
      scA[2*j] = aA; scA[2*j+1] = bA;
      scB[2*j] = aB; scB[2*j+1] = bB;
      if (aA < bvA){ bvA = aA; bcA = c0; }
      if (aB < bvB){ bvB = aB; bcB = c0; }
      if (bA < bvA){ bvA = bA; bcA = c0+1; }
      if (bB < bvB){ bvB = bB; bcB = c0+1; }
    }
    // pack + interleaved umin reduce
    uint uA = __float_as_uint(bvA);
    uA ^= (uA & 0x80000000u) ? 0xFFFFFFFFu : 0x80000000u;
    uint keyA = (uA & 0xFFFFFE00u) | ((uint)bcA & 511u);
    uint uB = __float_as_uint(bvB);
    uB ^= (uB & 0x80000000u) ? 0xFFFFFFFFu : 0x80000000u;
    uint keyB = (uB & 0xFFFFFE00u) | ((uint)bcB & 511u);
#pragma unroll
    for (int d=1; d<64; d<<=1){
      const uint okA = (uint)__shfl_xor((int)keyA, d);
      const uint okB = (uint)__shfl_xor((int)keyB, d);
      keyA = (okA < keyA) ? okA : keyA;
      keyB = (okB < keyB) ? okB : keyB;
    }
    const int mc0A = (int)(keyA & 511u);
    const int mc0B = (int)(keyB & 511u);
    const uint vqA = keyA & 0xFFFFFE00u;
    const uint vqB = keyB & 0xFFFFFE00u;
    const uint sbA = (vqA & 0x80000000u) ? (vqA ^ 0x80000000u) : ~vqA;
    const uint sbB = (vqB & 0x80000000u) ? (vqB ^ 0x80000000u) : ~vqB;
    const float beA = __uint_as_float(sbA);
    const float beB = __uint_as_float(sbB);
    const float thrA = beA + TAU, thrB = beB + TAU;

    int bmA = 0, bmB = 0;
#pragma unroll
    for (int k=0;k<8;k++){
      if (scA[k] <= thrA) bmA |= 1 << k;
      if (scB[k] <= thrB) bmB |= 1 << k;
    }
    const unsigned long long lmA = __ballot(bmA != 0);
    const unsigned long long lmB = __ballot(bmB != 0);
    const int b0A = __ffsll((long long)lmA) - 1;
    const int b0B = __ffsll((long long)lmB) - 1;
    const int bm0A = __shfl(bmA, b0A);
    const int bm0B = __shfl(bmB, b0B);
    const bool multiA = (__popcll(lmA) > 1) || ((bm0A & (bm0A-1)) != 0);
    const bool multiB = (__popcll(lmB) > 1) || ((bm0B & (bm0B-1)) != 0);

    int mcA = mc0A, mcB = mc0B;
    float sselA = beA + 768.f, sselB = beB + 768.f;

    if (multiA){
      float xv[12];
      {
        const float4* xp = (const float4*)(x + tokA*DIM + lane*12);
#pragma unroll
        for (int q=0;q<3;q++){
          const float4 v = xp[q];
          xv[q*4]=v.x; xv[q*4+1]=v.y; xv[q*4+2]=v.z; xv[q*4+3]=v.w;
        }
      }
      double bve = 1e300; int bce = 0x7fffffff;
      unsigned long long Lm = lmA;
      while (Lm){
        const int b = __ffsll((long long)Lm) - 1; Lm &= Lm - 1;
        const int mbits = __shfl(bmA, b);
#pragma unroll
        for (int k=0;k<8;k++){
          if (mbits & (1<<k)){
            const int c = (k>>1)*128 + b*2 + (k&1);
            const float dkv = __shfl((svA[k] - s0A[k]) * 0.5f, b);
            const float* __restrict__ crow = C32 + (size_t)c*DIM + lane*12;
            double dd = 0.0;
#pragma unroll
            for (int q=0;q<3;q++){
              const float4 v = *(const float4*)(crow + q*4);
              dd += (double)xv[q*4]*v.x + (double)xv[q*4+1]*v.y
                  + (double)xv[q*4+2]*v.z + (double)xv[q*4+3]*v.w;
            }
#pragma unroll
            for (int d=1; d<64; d<<=1) dd += __shfl_xor(dd, d);
            const double se = (double)cn[c] - 2.0*(dd - (double)dkv);
            if (se < bve || (se == bve && c < bce)){ bve = se; bce = c; }
          }
        }
      }
      mcA = bce; sselA = (float)bve;
    }
    if (multiB){
      float xv[12];
      {
        const float4* xp = (const float4*)(x + tokB*DIM + lane*12);
#pragma unroll
        for (int q=0;q<3;q++){
          const float4 v = xp[q];
          xv[q*4]=v.x; xv[q*4+1]=v.y; xv[q*4+2]=v.z; xv[q*4+3]=v.w;
        }
      }
      double bve = 1e300; int bce = 0x7fffffff;
      unsigned long long Lm = lmB;
      while (Lm){
        const int b = __ffsll((long long)Lm) - 1; Lm &= Lm - 1;
        const int mbits = __shfl(bmB, b);
#pragma unroll
        for (int k=0;k<8;k++){
          if (mbits & (1<<k)){
            const int c = (k>>1)*128 + b*2 + (k&1);
            const float dkv = __shfl((svB[k] - s0B[k]) * 0.5f, b);
            const float* __restrict__ crow = C32 + (size_t)c*DIM + lane*12;
            double dd = 0.0;
#pragma unroll
            for (int q=0;q<3;q++){
              const float4 v = *(const float4*)(crow + q*4);
              dd += (double)xv[q*4]*v.x + (double)xv[q*4+1]*v.y
                  + (double)xv[q*4+2]*v.z + (double)xv[q*4+3]*v.w;
            }
#pragma unroll
            for (int d=1; d<64; d<<=1) dd += __shfl_xor(dd, d);
            const double se = (double)cn[c] - 2.0*(dd - (double)dkv);
            if (se < bve || (se == bve && c < bce)){ bve = se; bce = c; }
          }
        }
      }
      mcB = bce; sselB = (float)bve;
    }

    mcsA[l] = mcA; mcsB[l] = mcB;
    if (FUSED) tot += (float)(8 - l) * (sselA + sselB);
    if (l < 7){
      const float* __restrict__ grA = G2 + (size_t)mcA*NCB;
      const float* __restrict__ grB = G2 + (size_t)mcB*NCB;
#pragma unroll
      for (int j=0;j<4;j++){
        const float2 gA = *(const float2*)(grA + j*128 + lane*2);
        const float2 gB = *(const float2*)(grB + j*128 + lane*2);
        svA[2*j] += gA.x; svA[2*j+1] += gA.y;
        svB[2*j] += gB.x; svB[2*j+1] += gB.y;
      }
    }
  }

  if (FUSED){
    // epilogue A then B: quantized = sum of 8 codeword rows
#pragma unroll
    for (int tb=0; tb<2; tb++){
      const size_t tok = tb ? tokB : tokA;
      const int* mcs = tb ? mcsB : mcsA;
      float q[12];
#pragma unroll
      for (int i=0;i<12;i++) q[i] = 0.f;
#pragma unroll
      for (int l=0;l<8;l++){
        const float* __restrict__ cw = C32 + (size_t)mcs[l]*DIM + lane*12;
#pragma unroll
        for (int qq=0;qq<3;qq++){
          const float4 v = *(const float4*)(cw + qq*4);
          q[qq*4]+=v.x; q[qq*4+1]+=v.y; q[qq*4+2]+=v.z; q[qq*4+3]+=v.w;
        }
      }
      float* op = out + tok*DIM + lane*12;
#pragma unroll
      for (int qq=0;qq<3;qq++){
        float4 v; v.x=q[qq*4]; v.y=q[qq*4+1]; v.z=q[qq*4+2]; v.w=q[qq*4+3];
        *(float4*)(op + qq*4) = v;
      }
    }
    // idx: lane0 writes A, lane1 writes B (mcs values wave-uniform)
    if (lane < 2){
      const int* mcs = lane ? mcsB : mcsA;
      const size_t tok = lane ? tokB : tokA;
      float4 i0, i1;
      i0.x=(float)(mcs[0]-0);   i0.y=(float)(mcs[1]-2);   i0.z=(float)(mcs[2]-6);   i0.w=(float)(mcs[3]-14);
      i1.x=(float)(mcs[4]-30);  i1.y=(float)(mcs[5]-62);  i1.z=(float)(mcs[6]-126); i1.w=(float)(mcs[7]-254);
      *(float4*)(out + (size_t)NTOK*DIM + tok*8)     = i0;
      *(float4*)(out + (size_t)NTOK*DIM + tok*8 + 4) = i1;
    }
    __shared__ float bs[8];
    if (lane == 0) bs[w] = tot;
    __syncthreads();
    if (t == 0){
      float s2 = 0.f;
#pragma unroll
      for (int j=0;j<8;j++) s2 += bs[j];
      part[blockIdx.x] = s2;
    }
  } else {
    if (lane < 2){
      const int* mcs = lane ? mcsB : mcsA;
      const size_t tok = lane ? tokB : tokA;
      int* idxw = (int*)(ws + WS_IDX);
      const int offs[8] = {0,2,6,14,30,62,126,254};
#pragma unroll
      for (int l=0;l<8;l++) idxw[tok*8 + l] = mcs[l] - offs[l];
    }
  }
}

// Fallback finalize (only when ws can't hold Sq and Sq lives in d_out).
__global__ __launch_bounds__(512) void k_fin(const float* __restrict__ x,
                                             char* __restrict__ ws,
                                             float* __restrict__ out,
                                             float* __restrict__ part){
  const int t = threadIdx.x, lane = t & 63, w = t >> 6;
  const size_t tok = (size_t)blockIdx.x * 8 + w;
  const int off[8] = {0,2,6,14,30,62,126,254};
  const int* __restrict__ idxw = (const int*)(ws + WS_IDX);
  const float* __restrict__ C32 = (const float*)(ws + WS_C32);
  int loc[8];
#pragma unroll
  for (int l=0;l<8;l++) loc[l] = idxw[tok*8 + l];
  if (lane < 8) out[(size_t)NTOK*DIM + tok*8 + lane] = (float)idxw[tok*8 + lane];

  const float4* __restrict__ xr = (const float4*)(x + tok*DIM);
  float4* __restrict__ qr = (float4*)(out + tok*DIM);
  const float4* crow[8];
#pragma unroll
  for (int l=0;l<8;l++) crow[l] = (const float4*)(C32 + (size_t)(loc[l] + off[l])*DIM);
  float ssq = 0.f;
#pragma unroll
  for (int i=0;i<3;i++){
    const int e4 = i*64 + lane;
    const float4 xv = xr[e4];
    float rx = xv.x, ry = xv.y, rz = xv.z, rw = xv.w;
    float qx = 0.f, qy = 0.f, qz = 0.f, qw = 0.f;
#pragma unroll
    for (int l=0;l<8;l++){
      const float4 cv = crow[l][e4];
      rx -= cv.x; ry -= cv.y; rz -= cv.z; rw -= cv.w;
      qx += cv.x; qy += cv.y; qz += cv.z; qw += cv.w;
      ssq += rx*rx + ry*ry + rz*rz + rw*rw;
    }
    float4 q; q.x = qx; q.y = qy; q.z = qz; q.w = qw;
    qr[e4] = q;
  }
#pragma unroll
  for (int d=32; d>0; d>>=1) ssq += __shfl_down(ssq, d);
  __shared__ float bsum[8];
  if (lane == 0) bsum[w] = ssq;
  __syncthreads();
  if (t == 0){
    float s2 = 0.f;
#pragma unroll
    for (int j=0;j<8;j++) s2 += bsum[j];
    part[blockIdx.x] = s2;
  }
}

// loss = 0.25 * (sum(part) + 8*sum(part2)) / (NTOK*DIM)   [part2 may be null-equiv]
__global__ void k_loss(const float* __restrict__ part, int n,
                       const float* __restrict__ part2, int n2,
                       float* __restrict__ out){
  const int t = threadIdx.x;
  double s = 0.0;
  for (int i=t; i<n; i+=256) s += (double)part[i];
  double sx = 0.0;
  for (int i=t; i<n2; i+=256) sx += (double)part2[i];
  __shared__ double red[256];
  red[t] = s + 8.0*sx; __syncthreads();
  for (int d=128; d>0; d>>=1){
    if (t < d) red[t] += red[t+d];
    __syncthreads();
  }
  if (t == 0)
    out[(size_t)NTOK*DIM + (size_t)NTOK*8] =
      (float)(0.25 * red[0] / (double)((size_t)NTOK * DIM));
}

extern "C" void kernel_launch(void* const* d_in, const int* in_sizes, int n_in,
                              void* d_out, int out_size, void* d_ws, size_t ws_size,
                              hipStream_t stream){
  const float* x = (const float*)d_in[0];
  char* ws = (char*)d_ws;
  float* out = (float*)d_out;
  float* part  = (float*)(ws + WS_PART);
  float* part2 = (float*)(ws + WS_PART2);
  const bool fused = ws_size >= (size_t)WS_S + (size_t)S_BYTES;
  _Float16* Sp = fused ? (_Float16*)(ws + WS_S) : (_Float16*)out;

  k_prep<<<512, 256, 0, stream>>>((const float*)d_in[1], (const float*)d_in[2],
                                  (const float*)d_in[3], (const float*)d_in[4],
                                  (const float*)d_in[5], (const float*)d_in[6],
                                  (const float*)d_in[7], (const float*)d_in[8], ws);
  k_gram<<<512, 256, 0, stream>>>(ws);
  k_gemm<<<2048, 256, 0, stream>>>(x, ws, Sp, part2);
  if (fused){
    k_chain<1><<<4096, 512, 0, stream>>>(x, Sp, ws, out, part);
    k_loss<<<1, 256, 0, stream>>>(part, 4096, part2, 2048, out);
  } else {
    k_chain<0><<<4096, 512, 0, stream>>>(x, Sp, ws, out, part);
    k_fin<<<8192, 512, 0, stream>>>(x, ws, out, part);
    k_loss<<<1, 256, 0, stream>>>(part, 8192, part2, 2048, out);
  }
}

// Round 16
// 362.115 us; speedup vs baseline: 1.2577x; 1.2577x over previous
//
#include <hip/hip_runtime.h>
#include <stdint.h>

#define NTOK 65536
#define DIM  768
#define NCB  512
#define NC   510
#define TAU  1.0f

typedef _Float16 f16x8 __attribute__((ext_vector_type(8)));
typedef float f32x4 __attribute__((ext_vector_type(4)));

// ws byte offsets
#define WS_C32   0u          // 512*768*4
#define WS_CHI   1572864u    // 512*768*2   (f16)
#define WS_CNORM 3145728u    // 512*4
#define WS_G     3147776u    // 512*512*4   (G2 = 2*Gram)
#define WS_IDX   4196352u    // 65536*8*4 (fallback path only)
#define WS_PART  6293504u    // 8192*4 chain loss partials
#define WS_PART2 6359040u    // 2048*4 gemm ||x||^2 partials
#define WS_S     8388608u    // Sq f16: 65536*512*2  (score-form)
#define S_BYTES  67108864u

__device__ __forceinline__ void gl_lds16(const void* g, void* l){
  __builtin_amdgcn_global_load_lds(
      (const __attribute__((address_space(1))) unsigned int*)g,
      (__attribute__((address_space(3))) unsigned int*)l,
      16, 0, 0);
}

__global__ void k_prep(const float* __restrict__ cb0, const float* __restrict__ cb1,
                       const float* __restrict__ cb2, const float* __restrict__ cb3,
                       const float* __restrict__ cb4, const float* __restrict__ cb5,
                       const float* __restrict__ cb6, const float* __restrict__ cb7,
                       char* __restrict__ ws){
  const int r = blockIdx.x, t = threadIdx.x;
  const float* srcs[8] = {cb0,cb1,cb2,cb3,cb4,cb5,cb6,cb7};
  const int off[8] = {0,2,6,14,30,62,126,254};
  const int KK[8]  = {2,4,8,16,32,64,128,256};
  const float* src = nullptr;
#pragma unroll
  for (int l=0;l<8;l++)
    if (r >= off[l] && r < off[l]+KK[l]) src = srcs[l] + (size_t)(r - off[l]) * DIM;
  float* C32 = (float*)(ws + WS_C32);
  _Float16* Chi = (_Float16*)(ws + WS_CHI);
  double ss = 0.0;
#pragma unroll
  for (int i=0;i<3;i++){
    const int e = t + i*256;
    const float v = src ? src[e] : 0.f;
    C32[(size_t)r*DIM + e] = v;
    Chi[(size_t)r*DIM + e] = (_Float16)v;
    ss += (double)v * (double)v;
  }
  __shared__ double red[256];
  red[t] = ss; __syncthreads();
  for (int sdown=128; sdown>0; sdown>>=1){
    if (t < sdown) red[t] += red[t+sdown];
    __syncthreads();
  }
  if (t == 0){
    float* cnp = (float*)(ws + WS_CNORM);
    cnp[r] = (r < NC) ? (float)red[0] : 1e30f;
  }
}

// G2 = 2 * C C^T (f64 accum)
__global__ void k_gram(char* __restrict__ ws){
  const int i = blockIdx.x, t = threadIdx.x;
  const float* __restrict__ C32 = (const float*)(ws + WS_C32);
  __shared__ float row[DIM];
  for (int e=t; e<DIM; e+=256) row[e] = C32[(size_t)i*DIM + e];
  __syncthreads();
  float* __restrict__ G = (float*)(ws + WS_G);
  for (int j=t; j<NCB; j+=256){
    const float4* cj = (const float4*)(C32 + (size_t)j*DIM);
    double d = 0.0;
    for (int k=0; k<DIM/4; k++){
      const float4 b = cj[k];
      d += (double)row[4*k]*(double)b.x + (double)row[4*k+1]*(double)b.y
         + (double)row[4*k+2]*(double)b.z + (double)row[4*k+3]*(double)b.w;
    }
    G[(size_t)i*NCB + j] = (float)(2.0*d);
  }
}

// Sq = f16(cn[c] - 2*(x . c) - 768), f16 MFMA, f32 accum. (R10 validated
// staging: A f32 + B f16 via global_load_lds, 48KB single-buffer.)
// Balanced ||x||^2: kt%4==nt slices from the staged f32 A-tile -> part2[bid].
__global__ __launch_bounds__(256, 3) void k_gemm(const float* __restrict__ x,
                                                 const char* __restrict__ ws,
                                                 _Float16* __restrict__ Sq,
                                                 float* __restrict__ part2){
  __shared__ __align__(16) char smem[49152];   // A f32 [128][64] @0, B f16 [128][64] @32768
  const int t = threadIdx.x, lane = t & 63, w = t >> 6;
  const int wm = w >> 1, wn = w & 1;
  const int bid = blockIdx.x;
  const int xcd = bid & 7, jj = bid >> 3;
  const int mt = xcd*64 + (jj >> 2), nt = jj & 3;
  const _Float16* __restrict__ Chi = (const _Float16*)(ws + WS_CHI);
  const float* __restrict__ cn = (const float*)(ws + WS_CNORM);

  f32x4 acc[4][4];
#pragma unroll
  for (int i=0;i<4;i++)
#pragma unroll
    for (int j=0;j<4;j++) acc[i][j] = {0.f,0.f,0.f,0.f};

  float xs = 0.f;

  for (int kt=0; kt<12; kt++){
    // stage A (f32): 8 issues x 4KB. dest linear; source granule pre-swizzled.
#pragma unroll
    for (int i8=0;i8<8;i8++){
      const int r0 = w*32 + i8*4;
      const int row = r0 + (lane>>4);
      const int g = lane & 15;
      const int sg = g ^ (((row&7)<<1) | ((row>>3)&1));
      const size_t go = (size_t)(mt*128 + row)*DIM + (size_t)kt*64 + sg*4;
      gl_lds16(x + go, smem + r0*256);
    }
    // stage B (f16): 4 issues x 4KB.
#pragma unroll
    for (int c4=0;c4<4;c4++){
      const int r0 = w*32 + c4*8;
      const int rloc = r0 + (lane>>3);
      const int jsrc = (lane&7) ^ (rloc&7);
      const size_t go = (size_t)(nt*128 + rloc)*DIM + (size_t)kt*64 + jsrc*8;
      gl_lds16(Chi + go, smem + 32768 + r0*128);
    }
    __syncthreads();
    if ((kt & 3) == nt){
      // balanced ||x||^2 slice from the staged f32 A-tile (order-independent)
#pragma unroll
      for (int g=0; g<8; g++){
        const f32x4 v = *(const f32x4*)(smem + t*128 + g*16);
        xs += v[0]*v[0] + v[1]*v[1] + v[2]*v[2] + v[3]*v[3];
      }
    }
#pragma unroll
    for (int kk=0; kk<2; kk++){
      f16x8 fa[4], fb[4];
#pragma unroll
      for (int mf=0;mf<4;mf++){
        const int m = wm*64 + mf*16 + (lane&15);
        const int maskm = ((m&7)<<1) | ((m>>3)&1);
        const int ch = kk*4 + (lane>>4);
        const int g0 = (2*ch) ^ maskm;
        const f32x4 lo = *(const f32x4*)(smem + m*256 + g0*16);
        const f32x4 hi = *(const f32x4*)(smem + m*256 + (g0^1)*16);
        f16x8 r;
        r[0]=(_Float16)lo[0]; r[1]=(_Float16)lo[1]; r[2]=(_Float16)lo[2]; r[3]=(_Float16)lo[3];
        r[4]=(_Float16)hi[0]; r[5]=(_Float16)hi[1]; r[6]=(_Float16)hi[2]; r[7]=(_Float16)hi[3];
        fa[mf] = r;
      }
#pragma unroll
      for (int nf=0;nf<4;nf++){
        const int c = wn*64 + nf*16 + (lane&15);
        const uint bb = (uint)(32768 + c*128 + ((((kk<<2)+(lane>>4)) ^ (c&7))*16));
        fb[nf] = *(const f16x8*)(smem + bb);
      }
#pragma unroll
      for (int mf=0;mf<4;mf++)
#pragma unroll
        for (int nf=0;nf<4;nf++)
          acc[mf][nf] = __builtin_amdgcn_mfma_f32_16x16x32_f16(fa[mf], fb[nf], acc[mf][nf], 0,0,0);
    }
    __syncthreads();
  }

  // block-reduce xs -> part2[bid]
#pragma unroll
  for (int d=32; d>0; d>>=1) xs += __shfl_down(xs, d);
  if (lane == 0) ((float*)smem)[w] = xs;
  __syncthreads();
  if (t == 0) part2[bid] = ((float*)smem)[0] + ((float*)smem)[1]
                         + ((float*)smem)[2] + ((float*)smem)[3];

  // epilogue: Sq = f16(cn[col] - 2*acc - 768)
#pragma unroll
  for (int mf=0;mf<4;mf++)
#pragma unroll
    for (int nf=0;nf<4;nf++){
      const f32x4 v = acc[mf][nf];
      const int col  = nt*128 + wn*64 + nf*16 + (lane&15);
      const int row0 = mt*128 + wm*64 + mf*16 + ((lane>>4)<<2);
      const float cnc = cn[col];
#pragma unroll
      for (int e=0;e<4;e++)
        Sq[(size_t)(row0+e)*NCB + col] = (_Float16)(cnc - 2.f*v[e] - 768.f);
    }
}

// Band-rescore argmin chain on stored SCORES (offset -768), 8 tokens/block.
// sc[8] (range-masked scores) computed once, reused for scan AND band mask.
// Gram-sum for rescore = (sv - s0)*0.5 (offsets cancel exactly).
template<int FUSED>
__global__ __launch_bounds__(512, 4) void k_chain(const float* __restrict__ x,
                                                  const _Float16* __restrict__ S,
                                                  char* __restrict__ ws,
                                                  float* __restrict__ out,
                                                  float* __restrict__ part){
  const int t = threadIdx.x, lane = t & 63, w = t >> 6;
  const size_t tok = (size_t)blockIdx.x*8 + w;
  const float* __restrict__ cn  = (const float*)(ws + WS_CNORM);
  const float* __restrict__ G2  = (const float*)(ws + WS_G);
  const float* __restrict__ C32 = (const float*)(ws + WS_C32);

  float sv[8], s0[8];
  {
    const uint* sp = (const uint*)(S + tok*NCB);
#pragma unroll
    for (int j=0;j<4;j++){
      union { uint u; _Float16 h[2]; } cv;
      cv.u = sp[j*64 + lane];
      sv[2*j]   = (float)cv.h[0];
      sv[2*j+1] = (float)cv.h[1];
    }
  }
#pragma unroll
  for (int k=0;k<8;k++) s0[k] = sv[k];

  int mcs[8];
  float tot = 0.f;

#pragma unroll
  for (int l=0; l<8; ++l){
    const int cs = (2<<l) - 2;
    const int ce = cs + (2<<l);
    float sc[8];
    float bv = 3e38f; int bc = 511;
#pragma unroll
    for (int j=0;j<4;j++){
      const int c0 = j*128 + lane*2;
      const float sA = (c0   >= cs && c0   < ce) ? sv[2*j]   : 3e38f;
      const float sB = (c0+1 >= cs && c0+1 < ce) ? sv[2*j+1] : 3e38f;
      sc[2*j] = sA; sc[2*j+1] = sB;
      if (sA < bv){ bv = sA; bc = c0; }
      if (sB < bv){ bv = sB; bc = c0+1; }
    }
    // pack: monotone-flip score, keep top 23 bits, 9-bit candidate id
    uint u = __float_as_uint(bv);
    u ^= (u & 0x80000000u) ? 0xFFFFFFFFu : 0x80000000u;
    uint key = (u & 0xFFFFFE00u) | ((uint)bc & 511u);
#pragma unroll
    for (int d=1; d<64; d<<=1){
      const uint ok = (uint)__shfl_xor((int)key, d);
      key = (ok < key) ? ok : key;
    }
    const int mc0 = (int)(key & 511u);
    const uint vq = key & 0xFFFFFE00u;
    const uint sb = (vq & 0x80000000u) ? (vq ^ 0x80000000u) : ~vq;
    const float bv_est = __uint_as_float(sb);   // quantized-down winner score
    const float thr = bv_est + TAU;

    // per-lane 8-bit band mask from the cached sc[]
    int bm = 0;
#pragma unroll
    for (int k=0;k<8;k++)
      if (sc[k] <= thr) bm |= 1 << k;
    const unsigned long long lmask = __ballot(bm != 0);
    const int b0 = __ffsll((long long)lmask) - 1;
    const int bm0 = __shfl(bm, b0);
    const bool multi = (__popcll(lmask) > 1) || ((bm0 & (bm0-1)) != 0);

    int mc = mc0;
    float ssel = bv_est + 768.f;     // true-scale score for loss
    if (multi){
      // rare exact-rescore path
      float xv[12];
      {
        const float4* xp = (const float4*)(x + tok*DIM + lane*12);
#pragma unroll
        for (int q=0;q<3;q++){
          const float4 v = xp[q];
          xv[q*4]=v.x; xv[q*4+1]=v.y; xv[q*4+2]=v.z; xv[q*4+3]=v.w;
        }
      }
      double bve = 1e300; int bce = 0x7fffffff;
      unsigned long long Lm = lmask;
      while (Lm){
        const int b = __ffsll((long long)Lm) - 1; Lm &= Lm - 1;
        const int mbits = __shfl(bm, b);
#pragma unroll
        for (int k=0;k<8;k++){
          if (mbits & (1<<k)){                      // wave-uniform branch, static k
            const int c = (k>>1)*128 + b*2 + (k&1);
            const float dkv = __shfl((sv[k] - s0[k]) * 0.5f, b);  // gram-corr sum
            const float* __restrict__ crow = C32 + (size_t)c*DIM + lane*12;
            double dd = 0.0;
#pragma unroll
            for (int q=0;q<3;q++){
              const float4 v = *(const float4*)(crow + q*4);
              dd += (double)xv[q*4]*v.x + (double)xv[q*4+1]*v.y
                  + (double)xv[q*4+2]*v.z + (double)xv[q*4+3]*v.w;
            }
#pragma unroll
            for (int d=1; d<64; d<<=1) dd += __shfl_xor(dd, d);
            const double se = (double)cn[c] - 2.0*(dd - (double)dkv);
            if (se < bve || (se == bve && c < bce)){ bve = se; bce = c; }
          }
        }
      }
      mc = bce;
      ssel = (float)bve;
    }
    mcs[l] = mc;
    if (FUSED) tot += (float)(8 - l) * ssel;
    if (l < 7){
      const float* __restrict__ gr = G2 + (size_t)mc*NCB;
#pragma unroll
      for (int j=0;j<4;j++){
        const float2 g2 = *(const float2*)(gr + j*128 + lane*2);
        sv[2*j] += g2.x; sv[2*j+1] += g2.y;
      }
    }
  }

  if (FUSED){
    // epilogue: quantized = sum of 8 codeword rows (independent gathers)
    float q[12];
#pragma unroll
    for (int i=0;i<12;i++) q[i] = 0.f;
#pragma unroll
    for (int l=0;l<8;l++){
      const float* __restrict__ cw = C32 + (size_t)mcs[l]*DIM + lane*12;
#pragma unroll
      for (int qq=0;qq<3;qq++){
        const float4 v = *(const float4*)(cw + qq*4);
        q[qq*4]+=v.x; q[qq*4+1]+=v.y; q[qq*4+2]+=v.z; q[qq*4+3]+=v.w;
      }
    }
    float* op = out + tok*DIM + lane*12;
#pragma unroll
    for (int qq=0;qq<3;qq++){
      float4 v; v.x=q[qq*4]; v.y=q[qq*4+1]; v.z=q[qq*4+2]; v.w=q[qq*4+3];
      *(float4*)(op + qq*4) = v;
    }
    if (lane == 0){
      float4 i0, i1;
      i0.x=(float)(mcs[0]-0);   i0.y=(float)(mcs[1]-2);   i0.z=(float)(mcs[2]-6);   i0.w=(float)(mcs[3]-14);
      i1.x=(float)(mcs[4]-30);  i1.y=(float)(mcs[5]-62);  i1.z=(float)(mcs[6]-126); i1.w=(float)(mcs[7]-254);
      *(float4*)(out + (size_t)NTOK*DIM + tok*8)     = i0;
      *(float4*)(out + (size_t)NTOK*DIM + tok*8 + 4) = i1;
    }
    __shared__ float bs[8];
    if (lane == 0) bs[w] = tot;
    __syncthreads();
    if (t == 0){
      float s2 = 0.f;
#pragma unroll
      for (int j=0;j<8;j++) s2 += bs[j];
      part[blockIdx.x] = s2;
    }
  } else {
    if (lane == 0){
      int* idxw = (int*)(ws + WS_IDX);
      const int offs[8] = {0,2,6,14,30,62,126,254};
#pragma unroll
      for (int l=0;l<8;l++) idxw[tok*8 + l] = mcs[l] - offs[l];
    }
  }
}

// Fallback finalize (only when ws can't hold Sq and Sq lives in d_out).
__global__ __launch_bounds__(512) void k_fin(const float* __restrict__ x,
                                             char* __restrict__ ws,
                                             float* __restrict__ out,
                                             float* __restrict__ part){
  const int t = threadIdx.x, lane = t & 63, w = t >> 6;
  const size_t tok = (size_t)blockIdx.x * 8 + w;
  const int off[8] = {0,2,6,14,30,62,126,254};
  const int* __restrict__ idxw = (const int*)(ws + WS_IDX);
  const float* __restrict__ C32 = (const float*)(ws + WS_C32);
  int loc[8];
#pragma unroll
  for (int l=0;l<8;l++) loc[l] = idxw[tok*8 + l];
  if (lane < 8) out[(size_t)NTOK*DIM + tok*8 + lane] = (float)idxw[tok*8 + lane];

  const float4* __restrict__ xr = (const float4*)(x + tok*DIM);
  float4* __restrict__ qr = (float4*)(out + tok*DIM);
  const float4* crow[8];
#pragma unroll
  for (int l=0;l<8;l++) crow[l] = (const float4*)(C32 + (size_t)(loc[l] + off[l])*DIM);
  float ssq = 0.f;
#pragma unroll
  for (int i=0;i<3;i++){
    const int e4 = i*64 + lane;
    const float4 xv = xr[e4];
    float rx = xv.x, ry = xv.y, rz = xv.z, rw = xv.w;
    float qx = 0.f, qy = 0.f, qz = 0.f, qw = 0.f;
#pragma unroll
    for (int l=0;l<8;l++){
      const float4 cv = crow[l][e4];
      rx -= cv.x; ry -= cv.y; rz -= cv.z; rw -= cv.w;
      qx += cv.x; qy += cv.y; qz += cv.z; qw += cv.w;
      ssq += rx*rx + ry*ry + rz*rz + rw*rw;
    }
    float4 q; q.x = qx; q.y = qy; q.z = qz; q.w = qw;
    qr[e4] = q;
  }
#pragma unroll
  for (int d=32; d>0; d>>=1) ssq += __shfl_down(ssq, d);
  __shared__ float bsum[8];
  if (lane == 0) bsum[w] = ssq;
  __syncthreads();
  if (t == 0){
    float s2 = 0.f;
#pragma unroll
    for (int j=0;j<8;j++) s2 += bsum[j];
    part[blockIdx.x] = s2;
  }
}

// loss = 0.25 * (sum(part) + 8*sum(part2)) / (NTOK*DIM)
__global__ void k_loss(const float* __restrict__ part, int n,
                       const float* __restrict__ part2, int n2,
                       float* __restrict__ out){
  const int t = threadIdx.x;
  double s = 0.0;
  for (int i=t; i<n; i+=256) s += (double)part[i];
  double sx = 0.0;
  for (int i=t; i<n2; i+=256) sx += (double)part2[i];
  __shared__ double red[256];
  red[t] = s + 8.0*sx; __syncthreads();
  for (int d=128; d>0; d>>=1){
    if (t < d) red[t] += red[t+d];
    __syncthreads();
  }
  if (t == 0)
    out[(size_t)NTOK*DIM + (size_t)NTOK*8] =
      (float)(0.25 * red[0] / (double)((size_t)NTOK * DIM));
}

extern "C" void kernel_launch(void* const* d_in, const int* in_sizes, int n_in,
                              void* d_out, int out_size, void* d_ws, size_t ws_size,
                              hipStream_t stream){
  const float* x = (const float*)d_in[0];
  char* ws = (char*)d_ws;
  float* out = (float*)d_out;
  float* part  = (float*)(ws + WS_PART);
  float* part2 = (float*)(ws + WS_PART2);
  const bool fused = ws_size >= (size_t)WS_S + (size_t)S_BYTES;
  _Float16* Sp = fused ? (_Float16*)(ws + WS_S) : (_Float16*)out;

  k_prep<<<512, 256, 0, stream>>>((const float*)d_in[1], (const float*)d_in[2],
                                  (const float*)d_in[3], (const float*)d_in[4],
                                  (const float*)d_in[5], (const float*)d_in[6],
                                  (const float*)d_in[7], (const float*)d_in[8], ws);
  k_gram<<<512, 256, 0, stream>>>(ws);
  k_gemm<<<2048, 256, 0, stream>>>(x, ws, Sp, part2);
  if (fused){
    k_chain<1><<<8192, 512, 0, stream>>>(x, Sp, ws, out, part);
    k_loss<<<1, 256, 0, stream>>>(part, 8192, part2, 2048, out);
  } else {
    k_chain<0><<<8192, 512, 0, stream>>>(x, Sp, ws, out, part);
    k_fin<<<8192, 512, 0, stream>>>(x, ws, out, part);
    k_loss<<<1, 256, 0, stream>>>(part, 8192, part2, 2048, out);
  }
}

// Round 17
// 358.934 us; speedup vs baseline: 1.2688x; 1.0089x over previous
//
#include <hip/hip_runtime.h>
#include <stdint.h>

#define NTOK 65536
#define DIM  768
#define NCB  512
#define NC   510
#define TAU  1.0f

typedef _Float16 f16x8 __attribute__((ext_vector_type(8)));
typedef float f32x4 __attribute__((ext_vector_type(4)));

// ws byte offsets
#define WS_C32   0u          // 512*768*4
#define WS_CHI   1572864u    // 512*768*2   (f16)
#define WS_CNORM 3145728u    // 512*4
#define WS_G     3147776u    // 512*512*4   (G2 = 2*Gram)
#define WS_IDX   4196352u    // 65536*8*4 (fallback path only)
#define WS_PART  6293504u    // 8192*4 chain loss partials
#define WS_PART2 6359040u    // 2048*4 gemm ||x||^2 partials
#define WS_S     8388608u    // Sq f16: 65536*512*2  (score-form)
#define S_BYTES  67108864u

__device__ __forceinline__ void gl_lds16(const void* g, void* l){
  __builtin_amdgcn_global_load_lds(
      (const __attribute__((address_space(1))) unsigned int*)g,
      (__attribute__((address_space(3))) unsigned int*)l,
      16, 0, 0);
}

__global__ void k_prep(const float* __restrict__ cb0, const float* __restrict__ cb1,
                       const float* __restrict__ cb2, const float* __restrict__ cb3,
                       const float* __restrict__ cb4, const float* __restrict__ cb5,
                       const float* __restrict__ cb6, const float* __restrict__ cb7,
                       char* __restrict__ ws){
  const int r = blockIdx.x, t = threadIdx.x;
  const float* srcs[8] = {cb0,cb1,cb2,cb3,cb4,cb5,cb6,cb7};
  const int off[8] = {0,2,6,14,30,62,126,254};
  const int KK[8]  = {2,4,8,16,32,64,128,256};
  const float* src = nullptr;
#pragma unroll
  for (int l=0;l<8;l++)
    if (r >= off[l] && r < off[l]+KK[l]) src = srcs[l] + (size_t)(r - off[l]) * DIM;
  float* C32 = (float*)(ws + WS_C32);
  _Float16* Chi = (_Float16*)(ws + WS_CHI);
  double ss = 0.0;
#pragma unroll
  for (int i=0;i<3;i++){
    const int e = t + i*256;
    const float v = src ? src[e] : 0.f;
    C32[(size_t)r*DIM + e] = v;
    Chi[(size_t)r*DIM + e] = (_Float16)v;
    ss += (double)v * (double)v;
  }
  __shared__ double red[256];
  red[t] = ss; __syncthreads();
  for (int sdown=128; sdown>0; sdown>>=1){
    if (t < sdown) red[t] += red[t+sdown];
    __syncthreads();
  }
  if (t == 0){
    float* cnp = (float*)(ws + WS_CNORM);
    cnp[r] = (r < NC) ? (float)red[0] : 1e30f;
  }
}

// G2 = 2 * C C^T (f64 accum)
__global__ void k_gram(char* __restrict__ ws){
  const int i = blockIdx.x, t = threadIdx.x;
  const float* __restrict__ C32 = (const float*)(ws + WS_C32);
  __shared__ float row[DIM];
  for (int e=t; e<DIM; e+=256) row[e] = C32[(size_t)i*DIM + e];
  __syncthreads();
  float* __restrict__ G = (float*)(ws + WS_G);
  for (int j=t; j<NCB; j+=256){
    const float4* cj = (const float4*)(C32 + (size_t)j*DIM);
    double d = 0.0;
    for (int k=0; k<DIM/4; k++){
      const float4 b = cj[k];
      d += (double)row[4*k]*(double)b.x + (double)row[4*k+1]*(double)b.y
         + (double)row[4*k+2]*(double)b.z + (double)row[4*k+3]*(double)b.w;
    }
    G[(size_t)i*NCB + j] = (float)(2.0*d);
  }
}

// Sq = f16(cn[c] - 2*(x . c) - 768), f16 MFMA, f32 accum. (R12-validated)
__global__ __launch_bounds__(256, 3) void k_gemm(const float* __restrict__ x,
                                                 const char* __restrict__ ws,
                                                 _Float16* __restrict__ Sq,
                                                 float* __restrict__ part2){
  __shared__ __align__(16) char smem[49152];   // A f32 [128][64] @0, B f16 [128][64] @32768
  const int t = threadIdx.x, lane = t & 63, w = t >> 6;
  const int wm = w >> 1, wn = w & 1;
  const int bid = blockIdx.x;
  const int xcd = bid & 7, jj = bid >> 3;
  const int mt = xcd*64 + (jj >> 2), nt = jj & 3;
  const _Float16* __restrict__ Chi = (const _Float16*)(ws + WS_CHI);
  const float* __restrict__ cn = (const float*)(ws + WS_CNORM);

  f32x4 acc[4][4];
#pragma unroll
  for (int i=0;i<4;i++)
#pragma unroll
    for (int j=0;j<4;j++) acc[i][j] = {0.f,0.f,0.f,0.f};

  float xs = 0.f;

  for (int kt=0; kt<12; kt++){
    // stage A (f32): 8 issues x 4KB. dest linear; source granule pre-swizzled.
#pragma unroll
    for (int i8=0;i8<8;i8++){
      const int r0 = w*32 + i8*4;
      const int row = r0 + (lane>>4);
      const int g = lane & 15;
      const int sg = g ^ (((row&7)<<1) | ((row>>3)&1));
      const size_t go = (size_t)(mt*128 + row)*DIM + (size_t)kt*64 + sg*4;
      gl_lds16(x + go, smem + r0*256);
    }
    // stage B (f16): 4 issues x 4KB.
#pragma unroll
    for (int c4=0;c4<4;c4++){
      const int r0 = w*32 + c4*8;
      const int rloc = r0 + (lane>>3);
      const int jsrc = (lane&7) ^ (rloc&7);
      const size_t go = (size_t)(nt*128 + rloc)*DIM + (size_t)kt*64 + jsrc*8;
      gl_lds16(Chi + go, smem + 32768 + r0*128);
    }
    __syncthreads();
    if ((kt & 3) == nt){
      // balanced ||x||^2 slice from the staged f32 A-tile (order-independent)
#pragma unroll
      for (int g=0; g<8; g++){
        const f32x4 v = *(const f32x4*)(smem + t*128 + g*16);
        xs += v[0]*v[0] + v[1]*v[1] + v[2]*v[2] + v[3]*v[3];
      }
    }
#pragma unroll
    for (int kk=0; kk<2; kk++){
      f16x8 fa[4], fb[4];
#pragma unroll
      for (int mf=0;mf<4;mf++){
        const int m = wm*64 + mf*16 + (lane&15);
        const int maskm = ((m&7)<<1) | ((m>>3)&1);
        const int ch = kk*4 + (lane>>4);
        const int g0 = (2*ch) ^ maskm;
        const f32x4 lo = *(const f32x4*)(smem + m*256 + g0*16);
        const f32x4 hi = *(const f32x4*)(smem + m*256 + (g0^1)*16);
        f16x8 r;
        r[0]=(_Float16)lo[0]; r[1]=(_Float16)lo[1]; r[2]=(_Float16)lo[2]; r[3]=(_Float16)lo[3];
        r[4]=(_Float16)hi[0]; r[5]=(_Float16)hi[1]; r[6]=(_Float16)hi[2]; r[7]=(_Float16)hi[3];
        fa[mf] = r;
      }
#pragma unroll
      for (int nf=0;nf<4;nf++){
        const int c = wn*64 + nf*16 + (lane&15);
        const uint bb = (uint)(32768 + c*128 + ((((kk<<2)+(lane>>4)) ^ (c&7))*16));
        fb[nf] = *(const f16x8*)(smem + bb);
      }
#pragma unroll
      for (int mf=0;mf<4;mf++)
#pragma unroll
        for (int nf=0;nf<4;nf++)
          acc[mf][nf] = __builtin_amdgcn_mfma_f32_16x16x32_f16(fa[mf], fb[nf], acc[mf][nf], 0,0,0);
    }
    __syncthreads();
  }

  // block-reduce xs -> part2[bid]
#pragma unroll
  for (int d=32; d>0; d>>=1) xs += __shfl_down(xs, d);
  if (lane == 0) ((float*)smem)[w] = xs;
  __syncthreads();
  if (t == 0) part2[bid] = ((float*)smem)[0] + ((float*)smem)[1]
                         + ((float*)smem)[2] + ((float*)smem)[3];

  // epilogue: Sq = f16(cn[col] - 2*acc - 768)
#pragma unroll
  for (int mf=0;mf<4;mf++)
#pragma unroll
    for (int nf=0;nf<4;nf++){
      const f32x4 v = acc[mf][nf];
      const int col  = nt*128 + wn*64 + nf*16 + (lane&15);
      const int row0 = mt*128 + wm*64 + mf*16 + ((lane>>4)<<2);
      const float cnc = cn[col];
#pragma unroll
      for (int e=0;e<4;e++)
        Sq[(size_t)(row0+e)*NCB + col] = (_Float16)(cnc - 2.f*v[e] - 768.f);
    }
}

// Band-rescore argmin chain on stored SCORES (offset -768), 8 tokens/block.
// Layer-adaptive argmin reduce: layer l's candidates span lanes
// [cs/2, (ce-1)/2] (2^l lanes for l<=5), so the butterfly only needs the
// minimal aligned window: steps {0,2,3,4,5,6,6,6}, + broadcast from the
// window's first valid lane for l<=4. Bit-identical result to the full
// 6-step reduce (invalid lanes carry +huge keys).
template<int FUSED>
__global__ __launch_bounds__(512, 4) void k_chain(const float* __restrict__ x,
                                                  const _Float16* __restrict__ S,
                                                  char* __restrict__ ws,
                                                  float* __restrict__ out,
                                                  float* __restrict__ part){
  const int t = threadIdx.x, lane = t & 63, w = t >> 6;
  const size_t tok = (size_t)blockIdx.x*8 + w;
  const float* __restrict__ cn  = (const float*)(ws + WS_CNORM);
  const float* __restrict__ G2  = (const float*)(ws + WS_G);
  const float* __restrict__ C32 = (const float*)(ws + WS_C32);

  float sv[8], s0[8];
  {
    const uint* sp = (const uint*)(S + tok*NCB);
#pragma unroll
    for (int j=0;j<4;j++){
      union { uint u; _Float16 h[2]; } cv;
      cv.u = sp[j*64 + lane];
      sv[2*j]   = (float)cv.h[0];
      sv[2*j+1] = (float)cv.h[1];
    }
  }
#pragma unroll
  for (int k=0;k<8;k++) s0[k] = sv[k];

  int mcs[8];
  float tot = 0.f;

  // adaptive reduce parameters per layer
  const int RSTEPS[8] = {0,2,3,4,5,6,6,6};
  const int RBCAST[8] = {0,1,3,7,15,-1,-1,-1};

#pragma unroll
  for (int l=0; l<8; ++l){
    const int cs = (2<<l) - 2;
    const int ce = cs + (2<<l);
    float sc[8];
    float bv = 3e38f; int bc = 511;
#pragma unroll
    for (int j=0;j<4;j++){
      const int c0 = j*128 + lane*2;
      const float sA = (c0   >= cs && c0   < ce) ? sv[2*j]   : 3e38f;
      const float sB = (c0+1 >= cs && c0+1 < ce) ? sv[2*j+1] : 3e38f;
      sc[2*j] = sA; sc[2*j+1] = sB;
      if (sA < bv){ bv = sA; bc = c0; }
      if (sB < bv){ bv = sB; bc = c0+1; }
    }
    // pack: monotone-flip score, keep top 23 bits, 9-bit candidate id
    uint u = __float_as_uint(bv);
    u ^= (u & 0x80000000u) ? 0xFFFFFFFFu : 0x80000000u;
    uint key = (u & 0xFFFFFE00u) | ((uint)bc & 511u);
    // layer-adaptive butterfly + optional broadcast
#pragma unroll
    for (int st=0; st<6; st++){
      if (st < RSTEPS[l]){
        const uint ok = (uint)__shfl_xor((int)key, 1<<st);
        key = (ok < key) ? ok : key;
      }
    }
    if (RBCAST[l] >= 0) key = (uint)__shfl((int)key, RBCAST[l]);
    const int mc0 = (int)(key & 511u);
    const uint vq = key & 0xFFFFFE00u;
    const uint sb = (vq & 0x80000000u) ? (vq ^ 0x80000000u) : ~vq;
    const float bv_est = __uint_as_float(sb);   // quantized-down winner score
    const float thr = bv_est + TAU;

    // per-lane 8-bit band mask from the cached sc[]
    int bm = 0;
#pragma unroll
    for (int k=0;k<8;k++)
      if (sc[k] <= thr) bm |= 1 << k;
    const unsigned long long lmask = __ballot(bm != 0);
    const int b0 = __ffsll((long long)lmask) - 1;
    const int bm0 = __shfl(bm, b0);
    const bool multi = (__popcll(lmask) > 1) || ((bm0 & (bm0-1)) != 0);

    int mc = mc0;
    float ssel = bv_est + 768.f;     // true-scale score for loss
    if (multi){
      // rare exact-rescore path
      float xv[12];
      {
        const float4* xp = (const float4*)(x + tok*DIM + lane*12);
#pragma unroll
        for (int q=0;q<3;q++){
          const float4 v = xp[q];
          xv[q*4]=v.x; xv[q*4+1]=v.y; xv[q*4+2]=v.z; xv[q*4+3]=v.w;
        }
      }
      double bve = 1e300; int bce = 0x7fffffff;
      unsigned long long Lm = lmask;
      while (Lm){
        const int b = __ffsll((long long)Lm) - 1; Lm &= Lm - 1;
        const int mbits = __shfl(bm, b);
#pragma unroll
        for (int k=0;k<8;k++){
          if (mbits & (1<<k)){                      // wave-uniform branch, static k
            const int c = (k>>1)*128 + b*2 + (k&1);
            const float dkv = __shfl((sv[k] - s0[k]) * 0.5f, b);  // gram-corr sum
            const float* __restrict__ crow = C32 + (size_t)c*DIM + lane*12;
            double dd = 0.0;
#pragma unroll
            for (int q=0;q<3;q++){
              const float4 v = *(const float4*)(crow + q*4);
              dd += (double)xv[q*4]*v.x + (double)xv[q*4+1]*v.y
                  + (double)xv[q*4+2]*v.z + (double)xv[q*4+3]*v.w;
            }
#pragma unroll
            for (int d=1; d<64; d<<=1) dd += __shfl_xor(dd, d);
            const double se = (double)cn[c] - 2.0*(dd - (double)dkv);
            if (se < bve || (se == bve && c < bce)){ bve = se; bce = c; }
          }
        }
      }
      mc = bce;
      ssel = (float)bve;
    }
    mcs[l] = mc;
    if (FUSED) tot += (float)(8 - l) * ssel;
    if (l < 7){
      const float* __restrict__ gr = G2 + (size_t)mc*NCB;
#pragma unroll
      for (int j=0;j<4;j++){
        const float2 g2 = *(const float2*)(gr + j*128 + lane*2);
        sv[2*j] += g2.x; sv[2*j+1] += g2.y;
      }
    }
  }

  if (FUSED){
    // epilogue: quantized = sum of 8 codeword rows (independent gathers)
    float q[12];
#pragma unroll
    for (int i=0;i<12;i++) q[i] = 0.f;
#pragma unroll
    for (int l=0;l<8;l++){
      const float* __restrict__ cw = C32 + (size_t)mcs[l]*DIM + lane*12;
#pragma unroll
      for (int qq=0;qq<3;qq++){
        const float4 v = *(const float4*)(cw + qq*4);
        q[qq*4]+=v.x; q[qq*4+1]+=v.y; q[qq*4+2]+=v.z; q[qq*4+3]+=v.w;
      }
    }
    float* op = out + tok*DIM + lane*12;
#pragma unroll
    for (int qq=0;qq<3;qq++){
      float4 v; v.x=q[qq*4]; v.y=q[qq*4+1]; v.z=q[qq*4+2]; v.w=q[qq*4+3];
      *(float4*)(op + qq*4) = v;
    }
    if (lane == 0){
      float4 i0, i1;
      i0.x=(float)(mcs[0]-0);   i0.y=(float)(mcs[1]-2);   i0.z=(float)(mcs[2]-6);   i0.w=(float)(mcs[3]-14);
      i1.x=(float)(mcs[4]-30);  i1.y=(float)(mcs[5]-62);  i1.z=(float)(mcs[6]-126); i1.w=(float)(mcs[7]-254);
      *(float4*)(out + (size_t)NTOK*DIM + tok*8)     = i0;
      *(float4*)(out + (size_t)NTOK*DIM + tok*8 + 4) = i1;
    }
    __shared__ float bs[8];
    if (lane == 0) bs[w] = tot;
    __syncthreads();
    if (t == 0){
      float s2 = 0.f;
#pragma unroll
      for (int j=0;j<8;j++) s2 += bs[j];
      part[blockIdx.x] = s2;
    }
  } else {
    if (lane == 0){
      int* idxw = (int*)(ws + WS_IDX);
      const int offs[8] = {0,2,6,14,30,62,126,254};
#pragma unroll
      for (int l=0;l<8;l++) idxw[tok*8 + l] = mcs[l] - offs[l];
    }
  }
}

// Fallback finalize (only when ws can't hold Sq and Sq lives in d_out).
__global__ __launch_bounds__(512) void k_fin(const float* __restrict__ x,
                                             char* __restrict__ ws,
                                             float* __restrict__ out,
                                             float* __restrict__ part){
  const int t = threadIdx.x, lane = t & 63, w = t >> 6;
  const size_t tok = (size_t)blockIdx.x * 8 + w;
  const int off[8] = {0,2,6,14,30,62,126,254};
  const int* __restrict__ idxw = (const int*)(ws + WS_IDX);
  const float* __restrict__ C32 = (const float*)(ws + WS_C32);
  int loc[8];
#pragma unroll
  for (int l=0;l<8;l++) loc[l] = idxw[tok*8 + l];
  if (lane < 8) out[(size_t)NTOK*DIM + tok*8 + lane] = (float)idxw[tok*8 + lane];

  const float4* __restrict__ xr = (const float4*)(x + tok*DIM);
  float4* __restrict__ qr = (float4*)(out + tok*DIM);
  const float4* crow[8];
#pragma unroll
  for (int l=0;l<8;l++) crow[l] = (const float4*)(C32 + (size_t)(loc[l] + off[l])*DIM);
  float ssq = 0.f;
#pragma unroll
  for (int i=0;i<3;i++){
    const int e4 = i*64 + lane;
    const float4 xv = xr[e4];
    float rx = xv.x, ry = xv.y, rz = xv.z, rw = xv.w;
    float qx = 0.f, qy = 0.f, qz = 0.f, qw = 0.f;
#pragma unroll
    for (int l=0;l<8;l++){
      const float4 cv = crow[l][e4];
      rx -= cv.x; ry -= cv.y; rz -= cv.z; rw -= cv.w;
      qx += cv.x; qy += cv.y; qz += cv.z; qw += cv.w;
      ssq += rx*rx + ry*ry + rz*rz + rw*rw;
    }
    float4 q; q.x = qx; q.y = qy; q.z = qz; q.w = qw;
    qr[e4] = q;
  }
#pragma unroll
  for (int d=32; d>0; d>>=1) ssq += __shfl_down(ssq, d);
  __shared__ float bsum[8];
  if (lane == 0) bsum[w] = ssq;
  __syncthreads();
  if (t == 0){
    float s2 = 0.f;
#pragma unroll
    for (int j=0;j<8;j++) s2 += bsum[j];
    part[blockIdx.x] = s2;
  }
}

// loss = 0.25 * (sum(part) + 8*sum(part2)) / (NTOK*DIM)
__global__ void k_loss(const float* __restrict__ part, int n,
                       const float* __restrict__ part2, int n2,
                       float* __restrict__ out){
  const int t = threadIdx.x;
  double s = 0.0;
  for (int i=t; i<n; i+=256) s += (double)part[i];
  double sx = 0.0;
  for (int i=t; i<n2; i+=256) sx += (double)part2[i];
  __shared__ double red[256];
  red[t] = s + 8.0*sx; __syncthreads();
  for (int d=128; d>0; d>>=1){
    if (t < d) red[t] += red[t+d];
    __syncthreads();
  }
  if (t == 0)
    out[(size_t)NTOK*DIM + (size_t)NTOK*8] =
      (float)(0.25 * red[0] / (double)((size_t)NTOK * DIM));
}

extern "C" void kernel_launch(void* const* d_in, const int* in_sizes, int n_in,
                              void* d_out, int out_size, void* d_ws, size_t ws_size,
                              hipStream_t stream){
  const float* x = (const float*)d_in[0];
  char* ws = (char*)d_ws;
  float* out = (float*)d_out;
  float* part  = (float*)(ws + WS_PART);
  float* part2 = (float*)(ws + WS_PART2);
  const bool fused = ws_size >= (size_t)WS_S + (size_t)S_BYTES;
  _Float16* Sp = fused ? (_Float16*)(ws + WS_S) : (_Float16*)out;

  k_prep<<<512, 256, 0, stream>>>((const float*)d_in[1], (const float*)d_in[2],
                                  (const float*)d_in[3], (const float*)d_in[4],
                                  (const float*)d_in[5], (const float*)d_in[6],
                                  (const float*)d_in[7], (const float*)d_in[8], ws);
  k_gram<<<512, 256, 0, stream>>>(ws);
  k_gemm<<<2048, 256, 0, stream>>>(x, ws, Sp, part2);
  if (fused){
    k_chain<1><<<8192, 512, 0, stream>>>(x, Sp, ws, out, part);
    k_loss<<<1, 256, 0, stream>>>(part, 8192, part2, 2048, out);
  } else {
    k_chain<0><<<8192, 512, 0, stream>>>(x, Sp, ws, out, part);
    k_fin<<<8192, 512, 0, stream>>>(x, ws, out, part);
    k_loss<<<1, 256, 0, stream>>>(part, 8192, part2, 2048, out);
  }
}